// Round 3
// baseline (67.162 us; speedup 1.0000x reference)
//
#include <hip/hip_runtime.h>

// Problem constants (fixed by the reference)
constexpr int Bsz  = 512;
constexpr int Nn   = 256;   // agents
constexpr int FINc = 32;
constexpr int H1c  = 16;
constexpr int Gc   = 8;
constexpr int FOUTc= 16;
constexpr int Kc   = 3;
constexpr int ACTc = 5;

// One block per batch element. 512 threads = 8 waves -> 16 waves/CU (2 blocks/CU).
// Wave w owns S rows [32w, 32w+32); lane owns columns 4*lane..4*lane+3 (float4).
__global__ __launch_bounds__(512, 4)
void cpn_kernel(const float* __restrict__ x,  const float* __restrict__ S,
                const float* __restrict__ W1, const float* __restrict__ b1,
                const float* __restrict__ W2, const float* __restrict__ b2,
                const float* __restrict__ Hgf,const float* __restrict__ bgf,
                const float* __restrict__ Wa, const float* __restrict__ ba,
                float* __restrict__ out)
{
    const int b    = blockIdx.x;
    const int tid  = threadIdx.x;
    const int wid  = tid >> 6;
    const int lane = tid & 63;
    const int n    = tid;            // agent index for phases A/C (tid < 256 only)

    __shared__ __align__(16) float zA[Nn][Gc];        // z0, n-major
    __shared__ __align__(16) float zB[Nn][Gc];        // z1, n-major
    __shared__ __align__(16) float zpart[4][Gc][Nn];  // merged partial sums (32 KB)

    // ---------------- Phase A: compress MLP (thread = agent n, tid<256) ----------------
    if (tid < Nn) {
        float xr[FINc];
        const float4* xp = reinterpret_cast<const float4*>(x + ((size_t)b * Nn + n) * FINc);
        #pragma unroll
        for (int i = 0; i < FINc / 4; ++i) {
            float4 v = xp[i];
            xr[4*i+0] = v.x; xr[4*i+1] = v.y; xr[4*i+2] = v.z; xr[4*i+3] = v.w;
        }
        float h1v[H1c];
        #pragma unroll
        for (int h = 0; h < H1c; ++h) {
            float a = b1[h];
            #pragma unroll
            for (int f = 0; f < FINc; ++f) a = fmaf(W1[h*FINc + f], xr[f], a);
            h1v[h] = fmaxf(a, 0.0f);
        }
        #pragma unroll
        for (int g = 0; g < Gc; ++g) {
            float a = b2[g];
            #pragma unroll
            for (int h = 0; h < H1c; ++h) a = fmaf(W2[g*H1c + h], h1v[h], a);
            zA[n][g] = fmaxf(a, 0.0f);
        }
    }
    __syncthreads();

    // ---------------- S passes: z_k = z_{k-1} @ S ----------------
    float z1r[Gc], z2r[Gc];

    auto spass = [&](const float (*zsrc)[Gc], float* zred) {
        float acc[Gc][4];
        #pragma unroll
        for (int g = 0; g < Gc; ++g)
            #pragma unroll
            for (int j = 0; j < 4; ++j) acc[g][j] = 0.0f;

        const float* sbase = S + ((size_t)b * Nn + wid * 32) * Nn + 4 * lane;

        // 4 chunks of 8 rows; explicit double-buffered float4 pipeline (8 loads in flight)
        float4 buf[8], nbuf[8];
        #pragma unroll
        for (int i = 0; i < 8; ++i) buf[i] = *reinterpret_cast<const float4*>(sbase + (size_t)i * Nn);
        #pragma unroll
        for (int c = 0; c < 4; ++c) {
            if (c < 3) {
                #pragma unroll
                for (int i = 0; i < 8; ++i)
                    nbuf[i] = *reinterpret_cast<const float4*>(sbase + (size_t)((c + 1) * 8 + i) * Nn);
            }
            #pragma unroll
            for (int i = 0; i < 8; ++i) {
                const int nn = wid * 32 + c * 8 + i;
                const float4 za = *reinterpret_cast<const float4*>(&zsrc[nn][0]); // LDS broadcast
                const float4 zb = *reinterpret_cast<const float4*>(&zsrc[nn][4]);
                const float zg[Gc] = {za.x, za.y, za.z, za.w, zb.x, zb.y, zb.z, zb.w};
                #pragma unroll
                for (int g = 0; g < Gc; ++g) {
                    acc[g][0] = fmaf(zg[g], buf[i].x, acc[g][0]);
                    acc[g][1] = fmaf(zg[g], buf[i].y, acc[g][1]);
                    acc[g][2] = fmaf(zg[g], buf[i].z, acc[g][2]);
                    acc[g][3] = fmaf(zg[g], buf[i].w, acc[g][3]);
                }
            }
            if (c < 3) {
                #pragma unroll
                for (int i = 0; i < 8; ++i) buf[i] = nbuf[i];
            }
        }

        // Two-phase merge: waves 0-3 write, waves 4-7 accumulate on top.
        if (wid < 4) {
            #pragma unroll
            for (int g = 0; g < Gc; ++g)
                *reinterpret_cast<float4*>(&zpart[wid][g][4 * lane]) =
                    make_float4(acc[g][0], acc[g][1], acc[g][2], acc[g][3]);
        }
        __syncthreads();
        if (wid >= 4) {
            #pragma unroll
            for (int g = 0; g < Gc; ++g) {
                float4 cur = *reinterpret_cast<const float4*>(&zpart[wid - 4][g][4 * lane]);
                cur.x += acc[g][0]; cur.y += acc[g][1]; cur.z += acc[g][2]; cur.w += acc[g][3];
                *reinterpret_cast<float4*>(&zpart[wid - 4][g][4 * lane]) = cur;
            }
        }
        __syncthreads();
        if (tid < Nn) {
            #pragma unroll
            for (int g = 0; g < Gc; ++g)   // stride-1 b32 reads, conflict-free
                zred[g] = (zpart[0][g][n] + zpart[1][g][n]) + (zpart[2][g][n] + zpart[3][g][n]);
        }
    };

    spass(zA, z1r);
    if (tid < Nn) {
        #pragma unroll
        for (int g = 0; g < Gc; ++g) zB[n][g] = z1r[g];    // publish z1 for pass 2
    }
    __syncthreads();                                        // guards zB publish + zpart reuse
    spass(zB, z2r);

    // ---------------- Phase C: graph filter + action head (tid<256) ----------------
    if (tid < Nn) {
        // z0 from zA, z1 from zB (LDS), z2 fresh in registers
        const float4 a0 = *reinterpret_cast<const float4*>(&zA[n][0]);
        const float4 a1 = *reinterpret_cast<const float4*>(&zA[n][4]);
        const float4 b0 = *reinterpret_cast<const float4*>(&zB[n][0]);
        const float4 b1v= *reinterpret_cast<const float4*>(&zB[n][4]);
        const float z0g[Gc] = {a0.x, a0.y, a0.z, a0.w, a1.x, a1.y, a1.z, a1.w};
        const float z1g[Gc] = {b0.x, b0.y, b0.z, b0.w, b1v.x, b1v.y, b1v.z, b1v.w};

        float y[FOUTc];
        #pragma unroll
        for (int f = 0; f < FOUTc; ++f) y[f] = bgf[f];
        #pragma unroll
        for (int g = 0; g < Gc; ++g) {
            #pragma unroll
            for (int f = 0; f < FOUTc; ++f) y[f] = fmaf(Hgf[f*(Kc*Gc) + 0*Gc + g], z0g[g], y[f]);
        }
        #pragma unroll
        for (int g = 0; g < Gc; ++g) {
            #pragma unroll
            for (int f = 0; f < FOUTc; ++f) y[f] = fmaf(Hgf[f*(Kc*Gc) + 1*Gc + g], z1g[g], y[f]);
        }
        #pragma unroll
        for (int g = 0; g < Gc; ++g) {
            #pragma unroll
            for (int f = 0; f < FOUTc; ++f) y[f] = fmaf(Hgf[f*(Kc*Gc) + 2*Gc + g], z2r[g], y[f]);
        }
        #pragma unroll
        for (int f = 0; f < FOUTc; ++f) y[f] = fmaxf(y[f], 0.0f);

        float* op = out + ((size_t)b * Nn + n) * ACTc;
        #pragma unroll
        for (int a = 0; a < ACTc; ++a) {
            float acc = ba[a];
            #pragma unroll
            for (int f = 0; f < FOUTc; ++f) acc = fmaf(Wa[a*FOUTc + f], y[f], acc);
            op[a] = acc;
        }
    }
}

extern "C" void kernel_launch(void* const* d_in, const int* in_sizes, int n_in,
                              void* d_out, int out_size, void* d_ws, size_t ws_size,
                              hipStream_t stream) {
    const float* x   = (const float*)d_in[0];
    const float* S   = (const float*)d_in[1];
    const float* W1  = (const float*)d_in[2];
    const float* b1  = (const float*)d_in[3];
    const float* W2  = (const float*)d_in[4];
    const float* b2  = (const float*)d_in[5];
    const float* Hgf = (const float*)d_in[6];
    const float* bgf = (const float*)d_in[7];
    const float* Wa  = (const float*)d_in[8];
    const float* ba  = (const float*)d_in[9];

    cpn_kernel<<<dim3(Bsz), dim3(512), 0, stream>>>(
        x, S, W1, b1, W2, b2, Hgf, bgf, Wa, ba, (float*)d_out);
}

// Round 4
// 58.911 us; speedup vs baseline: 1.1401x; 1.1401x over previous
//
#include <hip/hip_runtime.h>
#include <hip/hip_fp16.h>

// Problem constants (fixed by the reference)
constexpr int Bsz  = 512;
constexpr int Nn   = 256;   // agents
constexpr int FINc = 32;
constexpr int H1c  = 16;
constexpr int Gc   = 8;
constexpr int FOUTc= 16;
constexpr int Kc   = 3;
constexpr int ACTc = 5;

// One block per batch element. 512 threads = 8 waves -> 16 waves/CU (2 blocks/CU).
// Wave w owns S rows [32w, 32w+32); lane owns columns 4*lane..4*lane+3 (float4).
// z vectors stored in LDS as 8 x f16 (16 B) -> ONE ds_read_b128 per row.
__global__ __launch_bounds__(512, 4)
void cpn_kernel(const float* __restrict__ x,  const float* __restrict__ S,
                const float* __restrict__ W1, const float* __restrict__ b1,
                const float* __restrict__ W2, const float* __restrict__ b2,
                const float* __restrict__ Hgf,const float* __restrict__ bgf,
                const float* __restrict__ Wa, const float* __restrict__ ba,
                float* __restrict__ out)
{
    const int b    = blockIdx.x;
    const int tid  = threadIdx.x;
    const int wid  = tid >> 6;
    const int lane = tid & 63;
    const int n    = tid;            // agent index for phases A/C (tid < 256 only)

    __shared__ __align__(16) __half2 zA[Nn][4];       // z0 packed f16 (4 KB)
    __shared__ __align__(16) __half2 zB[Nn][4];       // z1 packed f16 (4 KB)
    __shared__ __align__(16) float zpart[4][Gc][Nn];  // merged partial sums (32 KB)

    // ---------------- Phase A: compress MLP (thread = agent n, tid<256) ----------------
    if (tid < Nn) {
        float xr[FINc];
        const float4* xp = reinterpret_cast<const float4*>(x + ((size_t)b * Nn + n) * FINc);
        #pragma unroll
        for (int i = 0; i < FINc / 4; ++i) {
            float4 v = xp[i];
            xr[4*i+0] = v.x; xr[4*i+1] = v.y; xr[4*i+2] = v.z; xr[4*i+3] = v.w;
        }
        float h1v[H1c];
        #pragma unroll
        for (int h = 0; h < H1c; ++h) {
            float a = b1[h];
            #pragma unroll
            for (int f = 0; f < FINc; ++f) a = fmaf(W1[h*FINc + f], xr[f], a);
            h1v[h] = fmaxf(a, 0.0f);
        }
        float z0v[Gc];
        #pragma unroll
        for (int g = 0; g < Gc; ++g) {
            float a = b2[g];
            #pragma unroll
            for (int h = 0; h < H1c; ++h) a = fmaf(W2[g*H1c + h], h1v[h], a);
            z0v[g] = fmaxf(a, 0.0f);
        }
        __half2 ph[4];
        #pragma unroll
        for (int g2 = 0; g2 < 4; ++g2) ph[g2] = __floats2half2_rn(z0v[2*g2], z0v[2*g2+1]);
        *reinterpret_cast<float4*>(&zA[n][0]) = *reinterpret_cast<const float4*>(ph);
    }
    __syncthreads();

    // ---------------- S passes: z_k = z_{k-1} @ S ----------------
    float z1r[Gc], z2r[Gc];

    auto spass = [&](const __half2 (*zsrc)[4], float* zred) {
        float acc[Gc][4];
        #pragma unroll
        for (int g = 0; g < Gc; ++g)
            #pragma unroll
            for (int j = 0; j < 4; ++j) acc[g][j] = 0.0f;

        const float* sbase = S + ((size_t)b * Nn + wid * 32) * Nn + 4 * lane;

        #pragma unroll 8
        for (int i = 0; i < 32; ++i) {
            const float4 sv = *reinterpret_cast<const float4*>(sbase + (size_t)i * Nn); // 16B/lane coalesced
            const int nn = wid * 32 + i;
            float4 raw = *reinterpret_cast<const float4*>(&zsrc[nn][0]);   // ONE b128 broadcast
            const __half2* hp = reinterpret_cast<const __half2*>(&raw);
            const float2 z01 = __half22float2(hp[0]);
            const float2 z23 = __half22float2(hp[1]);
            const float2 z45 = __half22float2(hp[2]);
            const float2 z67 = __half22float2(hp[3]);
            const float zg[Gc] = {z01.x, z01.y, z23.x, z23.y, z45.x, z45.y, z67.x, z67.y};
            #pragma unroll
            for (int g = 0; g < Gc; ++g) {
                acc[g][0] = fmaf(zg[g], sv.x, acc[g][0]);
                acc[g][1] = fmaf(zg[g], sv.y, acc[g][1]);
                acc[g][2] = fmaf(zg[g], sv.z, acc[g][2]);
                acc[g][3] = fmaf(zg[g], sv.w, acc[g][3]);
            }
        }

        // Two-phase merge: waves 0-3 write, waves 4-7 accumulate on top.
        if (wid < 4) {
            #pragma unroll
            for (int g = 0; g < Gc; ++g)
                *reinterpret_cast<float4*>(&zpart[wid][g][4 * lane]) =
                    make_float4(acc[g][0], acc[g][1], acc[g][2], acc[g][3]);
        }
        __syncthreads();
        if (wid >= 4) {
            #pragma unroll
            for (int g = 0; g < Gc; ++g) {
                float4 cur = *reinterpret_cast<const float4*>(&zpart[wid - 4][g][4 * lane]);
                cur.x += acc[g][0]; cur.y += acc[g][1]; cur.z += acc[g][2]; cur.w += acc[g][3];
                *reinterpret_cast<float4*>(&zpart[wid - 4][g][4 * lane]) = cur;
            }
        }
        __syncthreads();
        if (tid < Nn) {
            #pragma unroll
            for (int g = 0; g < Gc; ++g)   // stride-1 b32 reads, conflict-free
                zred[g] = (zpart[0][g][n] + zpart[1][g][n]) + (zpart[2][g][n] + zpart[3][g][n]);
        }
    };

    spass(zA, z1r);
    if (tid < Nn) {
        __half2 ph[4];
        #pragma unroll
        for (int g2 = 0; g2 < 4; ++g2) ph[g2] = __floats2half2_rn(z1r[2*g2], z1r[2*g2+1]);
        *reinterpret_cast<float4*>(&zB[n][0]) = *reinterpret_cast<const float4*>(ph);
    }
    __syncthreads();                                        // guards zB publish + zpart reuse
    spass(zB, z2r);

    // ---------------- Phase C: graph filter + action head (tid<256) ----------------
    if (tid < Nn) {
        float4 rawA = *reinterpret_cast<const float4*>(&zA[n][0]);
        float4 rawB = *reinterpret_cast<const float4*>(&zB[n][0]);
        const __half2* ha = reinterpret_cast<const __half2*>(&rawA);
        const __half2* hb = reinterpret_cast<const __half2*>(&rawB);
        float z0g[Gc], z1g[Gc];
        #pragma unroll
        for (int g2 = 0; g2 < 4; ++g2) {
            const float2 fa = __half22float2(ha[g2]);
            const float2 fb = __half22float2(hb[g2]);
            z0g[2*g2] = fa.x; z0g[2*g2+1] = fa.y;
            z1g[2*g2] = fb.x; z1g[2*g2+1] = fb.y;
        }

        float y[FOUTc];
        #pragma unroll
        for (int f = 0; f < FOUTc; ++f) y[f] = bgf[f];
        #pragma unroll
        for (int g = 0; g < Gc; ++g) {
            #pragma unroll
            for (int f = 0; f < FOUTc; ++f) y[f] = fmaf(Hgf[f*(Kc*Gc) + 0*Gc + g], z0g[g], y[f]);
        }
        #pragma unroll
        for (int g = 0; g < Gc; ++g) {
            #pragma unroll
            for (int f = 0; f < FOUTc; ++f) y[f] = fmaf(Hgf[f*(Kc*Gc) + 1*Gc + g], z1g[g], y[f]);
        }
        #pragma unroll
        for (int g = 0; g < Gc; ++g) {
            #pragma unroll
            for (int f = 0; f < FOUTc; ++f) y[f] = fmaf(Hgf[f*(Kc*Gc) + 2*Gc + g], z2r[g], y[f]);
        }
        #pragma unroll
        for (int f = 0; f < FOUTc; ++f) y[f] = fmaxf(y[f], 0.0f);

        float* op = out + ((size_t)b * Nn + n) * ACTc;
        #pragma unroll
        for (int a = 0; a < ACTc; ++a) {
            float acc = ba[a];
            #pragma unroll
            for (int f = 0; f < FOUTc; ++f) acc = fmaf(Wa[a*FOUTc + f], y[f], acc);
            op[a] = acc;
        }
    }
}

extern "C" void kernel_launch(void* const* d_in, const int* in_sizes, int n_in,
                              void* d_out, int out_size, void* d_ws, size_t ws_size,
                              hipStream_t stream) {
    const float* x   = (const float*)d_in[0];
    const float* S   = (const float*)d_in[1];
    const float* W1  = (const float*)d_in[2];
    const float* b1  = (const float*)d_in[3];
    const float* W2  = (const float*)d_in[4];
    const float* b2  = (const float*)d_in[5];
    const float* Hgf = (const float*)d_in[6];
    const float* bgf = (const float*)d_in[7];
    const float* Wa  = (const float*)d_in[8];
    const float* ba  = (const float*)d_in[9];

    cpn_kernel<<<dim3(Bsz), dim3(512), 0, stream>>>(
        x, S, W1, b1, W2, b2, Hgf, bgf, Wa, ba, (float*)d_out);
}